// Round 11
// baseline (132.159 us; speedup 1.0000x reference)
//
#include <hip/hip_runtime.h>
#include <cstdint>

// ExcitationShaper: segment-averaged params -> sigmoid/logspace maps -> gain ->
// fractional pluck comb -> time-varying RBJ low-pass biquad (TDF-II).
// Round-10 structure with one isolated change: compose/apply blocks go
// 256 -> 512 threads (4 samples/thread, 8 waves/block) -> 32 waves/CU
// (hardware max) and halved per-thread serial chains. The latency axis is
// the only one that has moved the number (round 9: SB 4096->2048, -7.7us).

namespace {
constexpr int B = 32;
constexpr int T = 65536;
constexpr int MAXSEG = 2048;      // >> expected ~66 onsets/row (p=1e-3)
constexpr int WV = 64;            // spans per row
constexpr int SPAN = T / WV;      // 1024 samples per span
constexpr int SB = 2048;          // samples per compose/apply block
constexpr int HALO = 256;         // > max comb lag (p < 200 -> lag <= 201)
constexpr int PARTS = T / SB;     // 32 parts per row
constexpr int NB = B * PARTS;     // 1024 blocks
constexpr int NT = 512;           // threads per compose/apply block (8 waves)
constexpr int NW = NT / 64;       // waves per block

constexpr float MIN_W_C  = 0.00785398163397448279f; // 2*pi*20/16000 = pi/400
constexpr float LOG2_400 = 8.64385618977472436f;    // log2(pi / MIN_W)
constexpr float LOG2_20  = 4.32192809488736235f;    // log2(2.0/0.1)

__device__ __forceinline__ float sigmoid_precise(float v) {
  return 1.0f / (1.0f + expf(-v));
}
__device__ __forceinline__ int pad16(int i) { return i + (i >> 4); }
} // namespace

// ---- K1: count onsets per (row, wave-span); int4 coalesced ----
__global__ void k_count(const int* __restrict__ onsets, int* __restrict__ cnt) {
  int gw = (blockIdx.x * blockDim.x + threadIdx.x) >> 6;
  int lane = threadIdx.x & 63;
  int b = gw / WV, wv = gw % WV;
  const int4* po = (const int4*)(onsets + b * T + wv * SPAN);
  int run = 0;
  for (int it = 0; it < SPAN / 256; ++it) {     // 4 iters, 16B/lane coalesced
    int4 v = po[it * 64 + lane];
    run += (v.x != 0) + (v.y != 0) + (v.z != 0) + (v.w != 0);
  }
  for (int off = 32; off; off >>= 1) run += __shfl_down(run, off);
  if (lane == 0) cnt[b * WV + wv] = run;
}

// ---- K2: seg ids (u16) + onset positions; span base via butterfly over cnt ----
__global__ void k_segids(const int* __restrict__ onsets, const int* __restrict__ cnt,
                         unsigned short* __restrict__ seg_ids, int* __restrict__ onsetPos,
                         int* __restrict__ nseg) {
  int gw = (blockIdx.x * blockDim.x + threadIdx.x) >> 6;
  int lane = threadIdx.x & 63;
  int b = gw / WV, wv = gw % WV;
  const int rb = b * T;
  int t0 = wv * SPAN;
  int cl = (lane < wv) ? cnt[b * WV + lane] : 0;
  int ct = cnt[b * WV + lane];
  for (int off = 1; off < 64; off <<= 1) {
    cl += __shfl_xor(cl, off);
    ct += __shfl_xor(ct, off);
  }
  if (wv == 0 && lane == 0) nseg[b] = ct;   // total onsets in row
  int run = cl;
  unsigned long long bm = (1ull << lane) - 1ull;
  for (int it = 0; it < SPAN / 64; ++it) {
    int t = t0 + it * 64 + lane;
    int o = onsets[rb + t] != 0;
    unsigned long long m = __ballot(o);
    int sid = run + __popcll(m & bm) + o;   // inclusive cumsum
    seg_ids[rb + t] = (unsigned short)min(sid, MAXSEG - 1);
    if (o && sid <= MAXSEG) onsetPos[b * MAXSEG + sid - 1] = t;
    run += __popcll(m);
  }
}

// ---- K3: per-segment average + full coefficient precompute (precise math) ----
__global__ void k_segavg(const float* __restrict__ params, const int* __restrict__ onsetPos,
                         const int* __restrict__ nseg, float4* __restrict__ segc,
                         float* __restrict__ segd) {
  __shared__ float part[4][4];
  int b = blockIdx.x >> 6;   // 64 blocks grid-stride over segments per row
  int s0 = blockIdx.x & 63;
  int tid = threadIdx.x;
  int n = nseg[b];
  const float4* pp = (const float4*)params;  // [B][T] float4
  for (int s = s0; s <= n; s += 64) {
    int start = (s == 0) ? 0 : onsetPos[b * MAXSEG + min(s, MAXSEG) - 1];
    int end   = (s == n) ? T : onsetPos[b * MAXSEG + min(s, MAXSEG - 1)];
    float a0 = 0.f, a1 = 0.f, a2 = 0.f, a3 = 0.f;
    for (int t = start + tid; t < end; t += 256) {
      float4 pv = pp[b * T + t];
      a0 += pv.x; a1 += pv.y; a2 += pv.z; a3 += pv.w;
    }
    for (int off = 32; off; off >>= 1) {
      a0 += __shfl_down(a0, off); a1 += __shfl_down(a1, off);
      a2 += __shfl_down(a2, off); a3 += __shfl_down(a3, off);
    }
    if ((tid & 63) == 0) {
      int w = tid >> 6;
      part[w][0] = a0; part[w][1] = a1; part[w][2] = a2; part[w][3] = a3;
    }
    __syncthreads();
    if (tid == 0) {
      float t0 = 0.f, t1 = 0.f, t2 = 0.f, t3 = 0.f;
      for (int w = 0; w < 4; ++w) {
        t0 += part[w][0]; t1 += part[w][1]; t2 += part[w][2]; t3 += part[w][3];
      }
      float inv = 1.0f / (float)max(end - start, 1);
      float av0 = t0 * inv, av1 = t1 * inv, av2 = t2 * inv, av3 = t3 * inv;
      float dist = 0.1f * exp2f(sigmoid_precise(av0) * LOG2_20);
      float wv   = MIN_W_C * exp2f(sigmoid_precise(av1) * LOG2_400);
      float qv   = 0.1f * exp2f(sigmoid_precise(av2) * LOG2_20);
      float mu   = sigmoid_precise(av3);
      float sw = sinf(wv), cw = cosf(wv);
      float alpha = sw / (2.0f * qv);
      float a0c = 1.0f + alpha;
      float b0 = (1.0f - cw) / (2.0f * a0c);
      float na1 = 2.0f * cw / a0c;          // -a1
      float na2 = (alpha - 1.0f) / a0c;     // -a2
      int sl = min(s, MAXSEG - 1);
      segc[b * MAXSEG + sl] = make_float4(mu, b0, na1, na2);
      segd[b * MAXSEG + sl] = dist;
    }
    __syncthreads();
  }
}

// ---- K4: comb + per-sample p0 + per-block affine aggregate ----
__global__ void __launch_bounds__(NT) k_compose(
    const float* __restrict__ f0, const float* __restrict__ x,
    const unsigned short* __restrict__ seg, const float4* __restrict__ segc,
    const float* __restrict__ segd, float* __restrict__ p0g,
    float* __restrict__ aggP) {
  __shared__ float s_xd[2448];   // pad16(SB+HALO)
  __shared__ float wagg[NW][6];
  int tid = threadIdx.x;
  int blk = blockIdx.x;
  int b = blk >> 5, part = blk & (PARTS - 1);
  int rb = b * T, rs = b * MAXSEG, bs = part * SB;

  // stage xd = x*dist (zeroed pre-row halo); coalesced, conflict-free
  for (int j = tid; j < SB + HALO; j += NT) {
    int tr = bs - HALO + j;
    float v = 0.f;
    if (tr >= 0) {
      int s = (int)seg[rb + tr];
      v = x[rb + tr] * segd[rs + s];
    }
    s_xd[pad16(j)] = v;
  }
  __syncthreads();

  int lane = tid & 63, w = tid >> 6;
  int t0l = tid * 4;
  float4 fv = *(const float4*)(f0 + rb + bs + t0l);
  uint2 sv = *(const uint2*)(seg + rb + bs + t0l);   // 4 u16
  unsigned sw_[2] = {sv.x, sv.y};
  float fs[4] = {fv.x, fv.y, fv.z, fv.w};
  float p0c[4];
  float A00 = 1.f, A01 = 0.f, A10 = 0.f, A11 = 1.f, d0 = 0.f, d1 = 0.f;
#pragma unroll
  for (int idx = 0; idx < 4; ++idx) {
    int li = t0l + idx;
    int s = (int)((sw_[idx >> 1] >> (16 * (idx & 1))) & 0xFFFFu);
    float4 sc = segc[rs + s];        // {mu, b0, -a1, -a2}
    float p = fs[idx] * sc.x;
    float z = floorf(p);
    float alfa = p - z;
    int zi = min((int)z, HALO - 8);  // defensive; p < 200 in practice
    int i1 = li - zi - 1 + HALO;
    float xl1 = s_xd[pad16(i1)];
    float xl2 = s_xd[pad16(i1 - 1)];
    float xc = s_xd[pad16(li + HALO)] - (1.f - alfa) * xl1 - alfa * xl2;
    float p0 = sc.y * xc;
    p0c[idx] = p0;
    float na1 = sc.z, na2 = sc.w;
    float c0v = p0 * (2.f + na1);
    float c1v = p0 * (1.f + na2);
    float nA00 = fmaf(na1, A00, A10);
    float nA01 = fmaf(na1, A01, A11);
    float nd0  = fmaf(na1, d0, d1 + c0v);
    float nA10 = na2 * A00;
    float nA11 = na2 * A01;
    float nd1  = fmaf(na2, d0, c1v);
    A00 = nA00; A01 = nA01; A10 = nA10; A11 = nA11; d0 = nd0; d1 = nd1;
  }
  *(float4*)(p0g + rb + bs + t0l) = make_float4(p0c[0], p0c[1], p0c[2], p0c[3]);
  // in-order shfl_down tree reduce -> lane 0 holds wave product (later∘earlier)
#pragma unroll
  for (int off = 1; off < 64; off <<= 1) {
    float R00 = __shfl_down(A00, off), R01 = __shfl_down(A01, off);
    float R10 = __shfl_down(A10, off), R11 = __shfl_down(A11, off);
    float Rd0 = __shfl_down(d0, off),  Rd1 = __shfl_down(d1, off);
    float n00 = fmaf(R00, A00, R01 * A10);
    float n01 = fmaf(R00, A01, R01 * A11);
    float n10 = fmaf(R10, A00, R11 * A10);
    float n11 = fmaf(R10, A01, R11 * A11);
    float nd0 = fmaf(R00, d0, fmaf(R01, d1, Rd0));
    float nd1 = fmaf(R10, d0, fmaf(R11, d1, Rd1));
    A00 = n00; A01 = n01; A10 = n10; A11 = n11; d0 = nd0; d1 = nd1;
  }
  if (lane == 0) {
    wagg[w][0] = A00; wagg[w][1] = A01; wagg[w][2] = A10;
    wagg[w][3] = A11; wagg[w][4] = d0;  wagg[w][5] = d1;
  }
  __syncthreads();
  if (tid == 0) {   // block aggregate = wave7∘...∘wave0
    float G00 = wagg[0][0], G01 = wagg[0][1], G10 = wagg[0][2];
    float G11 = wagg[0][3], Gd0 = wagg[0][4], Gd1 = wagg[0][5];
    for (int i = 1; i < NW; ++i) {
      float W00 = wagg[i][0], W01 = wagg[i][1], W10 = wagg[i][2];
      float W11 = wagg[i][3], Wd0 = wagg[i][4], Wd1 = wagg[i][5];
      float n00 = fmaf(W00, G00, W01 * G10);
      float n01 = fmaf(W00, G01, W01 * G11);
      float n10 = fmaf(W10, G00, W11 * G10);
      float n11 = fmaf(W10, G01, W11 * G11);
      float nd0 = fmaf(W00, Gd0, fmaf(W01, Gd1, Wd0));
      float nd1 = fmaf(W10, Gd0, fmaf(W11, Gd1, Wd1));
      G00 = n00; G01 = n01; G10 = n10; G11 = n11; Gd0 = nd0; Gd1 = nd1;
    }
    float* gp = aggP + blk * 6;
    gp[0] = G00; gp[1] = G01; gp[2] = G10; gp[3] = G11; gp[4] = Gd0; gp[5] = Gd1;
  }
}

// ---- K5: rebuild in-block scan from p0, serial row prefix, emit y ----
__global__ void __launch_bounds__(NT) k_apply(
    const float* __restrict__ p0g, const unsigned short* __restrict__ seg,
    const float4* __restrict__ segc, const float* __restrict__ aggP,
    float* __restrict__ out) {
  __shared__ float wagg[NW][6];
  __shared__ float rowpref[2];
  int tid = threadIdx.x;
  int blk = blockIdx.x;
  int b = blk >> 5, part = blk & (PARTS - 1);
  int rb = b * T, rs = b * MAXSEG, bs = part * SB;
  int lane = tid & 63, w = tid >> 6;
  int t0l = tid * 4;

  float4 pv = *(const float4*)(p0g + rb + bs + t0l);
  uint2 sv = *(const uint2*)(seg + rb + bs + t0l);
  unsigned sw_[2] = {sv.x, sv.y};
  float ps[4] = {pv.x, pv.y, pv.z, pv.w};
  float p0c[4], na1c[4], na2c[4];
  float A00 = 1.f, A01 = 0.f, A10 = 0.f, A11 = 1.f, d0 = 0.f, d1 = 0.f;
#pragma unroll
  for (int idx = 0; idx < 4; ++idx) {
    int s = (int)((sw_[idx >> 1] >> (16 * (idx & 1))) & 0xFFFFu);
    float4 sc = segc[rs + s];
    float p0 = ps[idx];
    float na1 = sc.z, na2 = sc.w;
    p0c[idx] = p0; na1c[idx] = na1; na2c[idx] = na2;
    float c0v = p0 * (2.f + na1);
    float c1v = p0 * (1.f + na2);
    float nA00 = fmaf(na1, A00, A10);
    float nA01 = fmaf(na1, A01, A11);
    float nd0  = fmaf(na1, d0, d1 + c0v);
    float nA10 = na2 * A00;
    float nA11 = na2 * A01;
    float nd1  = fmaf(na2, d0, c1v);
    A00 = nA00; A01 = nA01; A10 = nA10; A11 = nA11; d0 = nd0; d1 = nd1;
  }
  // wave-level inclusive Kogge-Stone
#pragma unroll
  for (int off = 1; off < 64; off <<= 1) {
    float P00 = __shfl_up(A00, off), P01 = __shfl_up(A01, off);
    float P10 = __shfl_up(A10, off), P11 = __shfl_up(A11, off);
    float Pd0 = __shfl_up(d0, off),  Pd1 = __shfl_up(d1, off);
    if (lane >= off) {
      float nA00 = fmaf(A00, P00, A01 * P10);
      float nA01 = fmaf(A00, P01, A01 * P11);
      float nA10 = fmaf(A10, P00, A11 * P10);
      float nA11 = fmaf(A10, P01, A11 * P11);
      float nd0  = fmaf(A00, Pd0, fmaf(A01, Pd1, d0));
      float nd1  = fmaf(A10, Pd0, fmaf(A11, Pd1, d1));
      A00 = nA00; A01 = nA01; A10 = nA10; A11 = nA11; d0 = nd0; d1 = nd1;
    }
  }
  if (lane == 63) {
    wagg[w][0] = A00; wagg[w][1] = A01; wagg[w][2] = A10;
    wagg[w][3] = A11; wagg[w][4] = d0;  wagg[w][5] = d1;
  }
  // row prefix from predecessor block aggregates (kernel boundary = sync)
  if (tid == 0) {
    float R00 = 1.f, R01 = 0.f, R10 = 0.f, R11 = 1.f, Rd0 = 0.f, Rd1 = 0.f;
    int base = (blk - part) * 6;        // first part of this row
    for (int j = 0; j < part; ++j) {
      const float* gp = aggP + base + j * 6;
      float W00 = gp[0], W01 = gp[1], W10 = gp[2], W11 = gp[3], Wd0 = gp[4], Wd1 = gp[5];
      float n00 = fmaf(W00, R00, W01 * R10);
      float n01 = fmaf(W00, R01, W01 * R11);
      float n10 = fmaf(W10, R00, W11 * R10);
      float n11 = fmaf(W10, R01, W11 * R11);
      float nd0 = fmaf(W00, Rd0, fmaf(W01, Rd1, Wd0));
      float nd1 = fmaf(W10, Rd0, fmaf(W11, Rd1, Wd1));
      R00 = n00; R01 = n01; R10 = n10; R11 = n11; Rd0 = nd0; Rd1 = nd1;
    }
    rowpref[0] = Rd0; rowpref[1] = Rd1;   // init state = 0 -> part-start state
  }
  __syncthreads();
  // per-lane exclusive (shift up 1; lane 0 = identity)
  float E00 = __shfl_up(A00, 1), E01 = __shfl_up(A01, 1);
  float E10 = __shfl_up(A10, 1), E11 = __shfl_up(A11, 1);
  float Ed0 = __shfl_up(d0, 1),  Ed1 = __shfl_up(d1, 1);
  if (lane == 0) { E00 = 1.f; E01 = 0.f; E10 = 0.f; E11 = 1.f; Ed0 = 0.f; Ed1 = 0.f; }
  // exclusive wave prefix P = waves 0..w-1 in order
  float P00 = 1.f, P01 = 0.f, P10 = 0.f, P11 = 1.f, Pd0 = 0.f, Pd1 = 0.f;
  for (int i = 0; i < w; ++i) {
    float W00 = wagg[i][0], W01 = wagg[i][1], W10 = wagg[i][2];
    float W11 = wagg[i][3], Wd0 = wagg[i][4], Wd1 = wagg[i][5];
    float n00 = fmaf(W00, P00, W01 * P10);
    float n01 = fmaf(W00, P01, W01 * P11);
    float n10 = fmaf(W10, P00, W11 * P10);
    float n11 = fmaf(W10, P01, W11 * P11);
    float nd0 = fmaf(W00, Pd0, fmaf(W01, Pd1, Wd0));
    float nd1 = fmaf(W10, Pd0, fmaf(W11, Pd1, Wd1));
    P00 = n00; P01 = n01; P10 = n10; P11 = n11; Pd0 = nd0; Pd1 = nd1;
  }
  // X = E after P (full in-block exclusive)
  float X00 = fmaf(E00, P00, E01 * P10);
  float X01 = fmaf(E00, P01, E01 * P11);
  float X10 = fmaf(E10, P00, E11 * P10);
  float X11 = fmaf(E10, P01, E11 * P11);
  float Xd0 = fmaf(E00, Pd0, fmaf(E01, Pd1, Ed0));
  float Xd1 = fmaf(E10, Pd0, fmaf(E11, Pd1, Ed1));
  // chunk-start state; apply
  float r0 = rowpref[0], r1 = rowpref[1];
  float s1 = fmaf(X00, r0, fmaf(X01, r1, Xd0));
  float s2 = fmaf(X10, r0, fmaf(X11, r1, Xd1));
  float ys[4];
#pragma unroll
  for (int idx = 0; idx < 4; ++idx) {
    float p0 = p0c[idx];
    float y = p0 + s1;
    ys[idx] = y;
    float ns1 = fmaf(na1c[idx], y, fmaf(2.f, p0, s2));
    float ns2 = fmaf(na2c[idx], y, p0);
    s1 = ns1; s2 = ns2;
  }
  *(float4*)(out + rb + bs + t0l) = make_float4(ys[0], ys[1], ys[2], ys[3]);
}

extern "C" void kernel_launch(void* const* d_in, const int* in_sizes, int n_in,
                              void* d_out, int out_size, void* d_ws, size_t ws_size,
                              hipStream_t stream) {
  const float* f0     = (const float*)d_in[0];
  const float* x      = (const float*)d_in[1];
  const float* params = (const float*)d_in[2];
  const int*   onsets = (const int*)d_in[3];
  float* out = (float*)d_out;

  char* w = (char*)d_ws;
  auto alloc = [&](size_t bytes) -> void* {
    void* p = (void*)w;
    w += (bytes + 255) & ~(size_t)255;
    return p;
  };
  unsigned short* seg_ids = (unsigned short*)alloc(sizeof(unsigned short) * B * T);
  int*    cnt      = (int*)alloc(sizeof(int) * B * WV);
  int*    onsetPos = (int*)alloc(sizeof(int) * B * MAXSEG);
  int*    nseg     = (int*)alloc(sizeof(int) * B);
  float4* segc     = (float4*)alloc(sizeof(float4) * B * MAXSEG);
  float*  segd     = (float*)alloc(sizeof(float) * B * MAXSEG);
  float*  p0g      = (float*)alloc(sizeof(float) * B * T);
  float*  aggP     = (float*)alloc(sizeof(float) * 6 * NB);
  (void)in_sizes; (void)n_in; (void)out_size; (void)ws_size;

  k_count  <<<512, 256, 0, stream>>>(onsets, cnt);
  k_segids <<<512, 256, 0, stream>>>(onsets, cnt, seg_ids, onsetPos, nseg);
  k_segavg <<<B * 64, 256, 0, stream>>>(params, onsetPos, nseg, segc, segd);
  k_compose<<<NB, NT, 0, stream>>>(f0, x, seg_ids, segc, segd, p0g, aggP);
  k_apply  <<<NB, NT, 0, stream>>>(p0g, seg_ids, segc, aggP, out);
}

// Round 12
// 127.744 us; speedup vs baseline: 1.0346x; 1.0346x over previous
//
#include <hip/hip_runtime.h>
#include <cstdint>

// ExcitationShaper: segment-averaged params -> sigmoid/logspace maps -> gain ->
// fractional pluck comb -> time-varying RBJ low-pass biquad (TDF-II).
// EMPIRICAL OPTIMUM (round 10, 130.53us): wide count/segids pair, segavg,
// compose (LDS comb tile -> p0 + per-block affine aggregate), apply (rebuild
// in-block scan from p0, serial row prefix over <=31 aggregates). SB=2048,
// 256-thread blocks, 8 samples/thread. Kernel boundaries are the grid
// barriers (in-kernel sync regressed 40-100us in rounds 5/6); 512-thread
// variant (R11) and narrow fused segids (R9) were neutral-or-worse.

namespace {
constexpr int B = 32;
constexpr int T = 65536;
constexpr int MAXSEG = 2048;      // >> expected ~66 onsets/row (p=1e-3)
constexpr int WV = 64;            // spans per row
constexpr int SPAN = T / WV;      // 1024 samples per span
constexpr int SB = 2048;          // samples per compose/apply block
constexpr int HALO = 256;         // > max comb lag (p < 200 -> lag <= 201)
constexpr int PARTS = T / SB;     // 32 parts per row
constexpr int NB = B * PARTS;     // 1024 blocks

constexpr float MIN_W_C  = 0.00785398163397448279f; // 2*pi*20/16000 = pi/400
constexpr float LOG2_400 = 8.64385618977472436f;    // log2(pi / MIN_W)
constexpr float LOG2_20  = 4.32192809488736235f;    // log2(2.0/0.1)

__device__ __forceinline__ float sigmoid_precise(float v) {
  return 1.0f / (1.0f + expf(-v));
}
__device__ __forceinline__ int pad16(int i) { return i + (i >> 4); }
} // namespace

// ---- K1: count onsets per (row, wave-span); int4 coalesced ----
__global__ void k_count(const int* __restrict__ onsets, int* __restrict__ cnt) {
  int gw = (blockIdx.x * blockDim.x + threadIdx.x) >> 6;
  int lane = threadIdx.x & 63;
  int b = gw / WV, wv = gw % WV;
  const int4* po = (const int4*)(onsets + b * T + wv * SPAN);
  int run = 0;
  for (int it = 0; it < SPAN / 256; ++it) {     // 4 iters, 16B/lane coalesced
    int4 v = po[it * 64 + lane];
    run += (v.x != 0) + (v.y != 0) + (v.z != 0) + (v.w != 0);
  }
  for (int off = 32; off; off >>= 1) run += __shfl_down(run, off);
  if (lane == 0) cnt[b * WV + wv] = run;
}

// ---- K2: seg ids (u16) + onset positions; span base via butterfly over cnt ----
__global__ void k_segids(const int* __restrict__ onsets, const int* __restrict__ cnt,
                         unsigned short* __restrict__ seg_ids, int* __restrict__ onsetPos,
                         int* __restrict__ nseg) {
  int gw = (blockIdx.x * blockDim.x + threadIdx.x) >> 6;
  int lane = threadIdx.x & 63;
  int b = gw / WV, wv = gw % WV;
  const int rb = b * T;
  int t0 = wv * SPAN;
  // base = sum of counts of spans 0..wv-1 (cnt is tiny -> L2-hot);
  // butterfly gives every lane the full masked sum
  int cl = (lane < wv) ? cnt[b * WV + lane] : 0;
  int ct = cnt[b * WV + lane];
  for (int off = 1; off < 64; off <<= 1) {
    cl += __shfl_xor(cl, off);
    ct += __shfl_xor(ct, off);
  }
  if (wv == 0 && lane == 0) nseg[b] = ct;   // total onsets in row
  int run = cl;
  unsigned long long bm = (1ull << lane) - 1ull;
  for (int it = 0; it < SPAN / 64; ++it) {
    int t = t0 + it * 64 + lane;
    int o = onsets[rb + t] != 0;
    unsigned long long m = __ballot(o);
    int sid = run + __popcll(m & bm) + o;   // inclusive cumsum
    seg_ids[rb + t] = (unsigned short)min(sid, MAXSEG - 1);
    if (o && sid <= MAXSEG) onsetPos[b * MAXSEG + sid - 1] = t;
    run += __popcll(m);
  }
}

// ---- K3: per-segment average + full coefficient precompute (precise math) ----
__global__ void k_segavg(const float* __restrict__ params, const int* __restrict__ onsetPos,
                         const int* __restrict__ nseg, float4* __restrict__ segc,
                         float* __restrict__ segd) {
  __shared__ float part[4][4];
  int b = blockIdx.x >> 6;   // 64 blocks grid-stride over segments per row
  int s0 = blockIdx.x & 63;
  int tid = threadIdx.x;
  int n = nseg[b];
  const float4* pp = (const float4*)params;  // [B][T] float4
  for (int s = s0; s <= n; s += 64) {
    int start = (s == 0) ? 0 : onsetPos[b * MAXSEG + min(s, MAXSEG) - 1];
    int end   = (s == n) ? T : onsetPos[b * MAXSEG + min(s, MAXSEG - 1)];
    float a0 = 0.f, a1 = 0.f, a2 = 0.f, a3 = 0.f;
    for (int t = start + tid; t < end; t += 256) {
      float4 pv = pp[b * T + t];
      a0 += pv.x; a1 += pv.y; a2 += pv.z; a3 += pv.w;
    }
    for (int off = 32; off; off >>= 1) {
      a0 += __shfl_down(a0, off); a1 += __shfl_down(a1, off);
      a2 += __shfl_down(a2, off); a3 += __shfl_down(a3, off);
    }
    if ((tid & 63) == 0) {
      int w = tid >> 6;
      part[w][0] = a0; part[w][1] = a1; part[w][2] = a2; part[w][3] = a3;
    }
    __syncthreads();
    if (tid == 0) {
      float t0 = 0.f, t1 = 0.f, t2 = 0.f, t3 = 0.f;
      for (int w = 0; w < 4; ++w) {
        t0 += part[w][0]; t1 += part[w][1]; t2 += part[w][2]; t3 += part[w][3];
      }
      float inv = 1.0f / (float)max(end - start, 1);
      float av0 = t0 * inv, av1 = t1 * inv, av2 = t2 * inv, av3 = t3 * inv;
      float dist = 0.1f * exp2f(sigmoid_precise(av0) * LOG2_20);
      float wv   = MIN_W_C * exp2f(sigmoid_precise(av1) * LOG2_400);
      float qv   = 0.1f * exp2f(sigmoid_precise(av2) * LOG2_20);
      float mu   = sigmoid_precise(av3);
      float sw = sinf(wv), cw = cosf(wv);
      float alpha = sw / (2.0f * qv);
      float a0c = 1.0f + alpha;
      float b0 = (1.0f - cw) / (2.0f * a0c);
      float na1 = 2.0f * cw / a0c;          // -a1
      float na2 = (alpha - 1.0f) / a0c;     // -a2
      int sl = min(s, MAXSEG - 1);
      segc[b * MAXSEG + sl] = make_float4(mu, b0, na1, na2);
      segd[b * MAXSEG + sl] = dist;
    }
    __syncthreads();
  }
}

// ---- K4: comb + per-sample p0 + per-block affine aggregate ----
__global__ void __launch_bounds__(256) k_compose(
    const float* __restrict__ f0, const float* __restrict__ x,
    const unsigned short* __restrict__ seg, const float4* __restrict__ segc,
    const float* __restrict__ segd, float* __restrict__ p0g,
    float* __restrict__ aggP) {
  __shared__ float s_xd[2448];   // pad16(SB+HALO)
  __shared__ float wagg[4][6];
  int tid = threadIdx.x;
  int blk = blockIdx.x;
  int b = blk >> 5, part = blk & (PARTS - 1);
  int rb = b * T, rs = b * MAXSEG, bs = part * SB;

  // stage xd = x*dist (zeroed pre-row halo); coalesced, conflict-free
  for (int j = tid; j < SB + HALO; j += 256) {
    int tr = bs - HALO + j;
    float v = 0.f;
    if (tr >= 0) {
      int s = (int)seg[rb + tr];
      v = x[rb + tr] * segd[rs + s];
    }
    s_xd[pad16(j)] = v;
  }
  __syncthreads();

  int lane = tid & 63, w = tid >> 6;
  int t0l = tid * 8;
  const float4* f4 = (const float4*)(f0 + rb + bs + t0l);
  const uint4* sg4 = (const uint4*)(seg + rb + bs + t0l);   // 8 u16
  uint4 sv = sg4[0];
  unsigned sw_[4] = {sv.x, sv.y, sv.z, sv.w};
  float p0c[8];
  float A00 = 1.f, A01 = 0.f, A10 = 0.f, A11 = 1.f, d0 = 0.f, d1 = 0.f;
#pragma unroll
  for (int k = 0; k < 2; ++k) {
    float4 fv = f4[k];
    float fs[4] = {fv.x, fv.y, fv.z, fv.w};
#pragma unroll
    for (int q = 0; q < 4; ++q) {
      int idx = k * 4 + q;
      int li = t0l + idx;
      int s = (int)((sw_[idx >> 1] >> (16 * (idx & 1))) & 0xFFFFu);
      float4 sc = segc[rs + s];        // {mu, b0, -a1, -a2}
      float p = fs[q] * sc.x;
      float z = floorf(p);
      float alfa = p - z;
      int zi = min((int)z, HALO - 8);  // defensive; p < 200 in practice
      int i1 = li - zi - 1 + HALO;
      float xl1 = s_xd[pad16(i1)];
      float xl2 = s_xd[pad16(i1 - 1)];
      float xc = s_xd[pad16(li + HALO)] - (1.f - alfa) * xl1 - alfa * xl2;
      float p0 = sc.y * xc;
      p0c[idx] = p0;
      float na1 = sc.z, na2 = sc.w;
      float c0v = p0 * (2.f + na1);
      float c1v = p0 * (1.f + na2);
      float nA00 = fmaf(na1, A00, A10);
      float nA01 = fmaf(na1, A01, A11);
      float nd0  = fmaf(na1, d0, d1 + c0v);
      float nA10 = na2 * A00;
      float nA11 = na2 * A01;
      float nd1  = fmaf(na2, d0, c1v);
      A00 = nA00; A01 = nA01; A10 = nA10; A11 = nA11; d0 = nd0; d1 = nd1;
    }
  }
  float4* pp4 = (float4*)(p0g + rb + bs + t0l);
  pp4[0] = make_float4(p0c[0], p0c[1], p0c[2], p0c[3]);
  pp4[1] = make_float4(p0c[4], p0c[5], p0c[6], p0c[7]);
  // in-order shfl_down tree reduce -> lane 0 holds wave product (later∘earlier)
#pragma unroll
  for (int off = 1; off < 64; off <<= 1) {
    float R00 = __shfl_down(A00, off), R01 = __shfl_down(A01, off);
    float R10 = __shfl_down(A10, off), R11 = __shfl_down(A11, off);
    float Rd0 = __shfl_down(d0, off),  Rd1 = __shfl_down(d1, off);
    float n00 = fmaf(R00, A00, R01 * A10);
    float n01 = fmaf(R00, A01, R01 * A11);
    float n10 = fmaf(R10, A00, R11 * A10);
    float n11 = fmaf(R10, A01, R11 * A11);
    float nd0 = fmaf(R00, d0, fmaf(R01, d1, Rd0));
    float nd1 = fmaf(R10, d0, fmaf(R11, d1, Rd1));
    A00 = n00; A01 = n01; A10 = n10; A11 = n11; d0 = nd0; d1 = nd1;
  }
  if (lane == 0) {
    wagg[w][0] = A00; wagg[w][1] = A01; wagg[w][2] = A10;
    wagg[w][3] = A11; wagg[w][4] = d0;  wagg[w][5] = d1;
  }
  __syncthreads();
  if (tid == 0) {   // block aggregate = wave3∘wave2∘wave1∘wave0
    float G00 = wagg[0][0], G01 = wagg[0][1], G10 = wagg[0][2];
    float G11 = wagg[0][3], Gd0 = wagg[0][4], Gd1 = wagg[0][5];
    for (int i = 1; i < 4; ++i) {
      float W00 = wagg[i][0], W01 = wagg[i][1], W10 = wagg[i][2];
      float W11 = wagg[i][3], Wd0 = wagg[i][4], Wd1 = wagg[i][5];
      float n00 = fmaf(W00, G00, W01 * G10);
      float n01 = fmaf(W00, G01, W01 * G11);
      float n10 = fmaf(W10, G00, W11 * G10);
      float n11 = fmaf(W10, G01, W11 * G11);
      float nd0 = fmaf(W00, Gd0, fmaf(W01, Gd1, Wd0));
      float nd1 = fmaf(W10, Gd0, fmaf(W11, Gd1, Wd1));
      G00 = n00; G01 = n01; G10 = n10; G11 = n11; Gd0 = nd0; Gd1 = nd1;
    }
    float* gp = aggP + blk * 6;
    gp[0] = G00; gp[1] = G01; gp[2] = G10; gp[3] = G11; gp[4] = Gd0; gp[5] = Gd1;
  }
}

// ---- K5: rebuild in-block scan from p0, serial row prefix, emit y ----
__global__ void __launch_bounds__(256) k_apply(
    const float* __restrict__ p0g, const unsigned short* __restrict__ seg,
    const float4* __restrict__ segc, const float* __restrict__ aggP,
    float* __restrict__ out) {
  __shared__ float wagg[4][6];
  __shared__ float rowpref[2];
  int tid = threadIdx.x;
  int blk = blockIdx.x;
  int b = blk >> 5, part = blk & (PARTS - 1);
  int rb = b * T, rs = b * MAXSEG, bs = part * SB;
  int lane = tid & 63, w = tid >> 6;
  int t0l = tid * 8;

  const float4* pp4 = (const float4*)(p0g + rb + bs + t0l);
  const uint4* sg4 = (const uint4*)(seg + rb + bs + t0l);
  uint4 sv = sg4[0];
  unsigned sw_[4] = {sv.x, sv.y, sv.z, sv.w};
  float p0c[8], na1c[8], na2c[8];
  float A00 = 1.f, A01 = 0.f, A10 = 0.f, A11 = 1.f, d0 = 0.f, d1 = 0.f;
#pragma unroll
  for (int k = 0; k < 2; ++k) {
    float4 pv = pp4[k];
    float ps[4] = {pv.x, pv.y, pv.z, pv.w};
#pragma unroll
    for (int q = 0; q < 4; ++q) {
      int idx = k * 4 + q;
      int s = (int)((sw_[idx >> 1] >> (16 * (idx & 1))) & 0xFFFFu);
      float4 sc = segc[rs + s];
      float p0 = ps[q];
      float na1 = sc.z, na2 = sc.w;
      p0c[idx] = p0; na1c[idx] = na1; na2c[idx] = na2;
      float c0v = p0 * (2.f + na1);
      float c1v = p0 * (1.f + na2);
      float nA00 = fmaf(na1, A00, A10);
      float nA01 = fmaf(na1, A01, A11);
      float nd0  = fmaf(na1, d0, d1 + c0v);
      float nA10 = na2 * A00;
      float nA11 = na2 * A01;
      float nd1  = fmaf(na2, d0, c1v);
      A00 = nA00; A01 = nA01; A10 = nA10; A11 = nA11; d0 = nd0; d1 = nd1;
    }
  }
  // wave-level inclusive Kogge-Stone
#pragma unroll
  for (int off = 1; off < 64; off <<= 1) {
    float P00 = __shfl_up(A00, off), P01 = __shfl_up(A01, off);
    float P10 = __shfl_up(A10, off), P11 = __shfl_up(A11, off);
    float Pd0 = __shfl_up(d0, off),  Pd1 = __shfl_up(d1, off);
    if (lane >= off) {
      float nA00 = fmaf(A00, P00, A01 * P10);
      float nA01 = fmaf(A00, P01, A01 * P11);
      float nA10 = fmaf(A10, P00, A11 * P10);
      float nA11 = fmaf(A10, P01, A11 * P11);
      float nd0  = fmaf(A00, Pd0, fmaf(A01, Pd1, d0));
      float nd1  = fmaf(A10, Pd0, fmaf(A11, Pd1, d1));
      A00 = nA00; A01 = nA01; A10 = nA10; A11 = nA11; d0 = nd0; d1 = nd1;
    }
  }
  if (lane == 63) {
    wagg[w][0] = A00; wagg[w][1] = A01; wagg[w][2] = A10;
    wagg[w][3] = A11; wagg[w][4] = d0;  wagg[w][5] = d1;
  }
  // row prefix from predecessor block aggregates (kernel boundary = sync);
  // loads are independent -> compiler pipelines them
  if (tid == 0) {
    float R00 = 1.f, R01 = 0.f, R10 = 0.f, R11 = 1.f, Rd0 = 0.f, Rd1 = 0.f;
    int base = (blk - part) * 6;        // first part of this row
    for (int j = 0; j < part; ++j) {
      const float* gp = aggP + base + j * 6;
      float W00 = gp[0], W01 = gp[1], W10 = gp[2], W11 = gp[3], Wd0 = gp[4], Wd1 = gp[5];
      float n00 = fmaf(W00, R00, W01 * R10);
      float n01 = fmaf(W00, R01, W01 * R11);
      float n10 = fmaf(W10, R00, W11 * R10);
      float n11 = fmaf(W10, R01, W11 * R11);
      float nd0 = fmaf(W00, Rd0, fmaf(W01, Rd1, Wd0));
      float nd1 = fmaf(W10, Rd0, fmaf(W11, Rd1, Wd1));
      R00 = n00; R01 = n01; R10 = n10; R11 = n11; Rd0 = nd0; Rd1 = nd1;
    }
    rowpref[0] = Rd0; rowpref[1] = Rd1;   // init state = 0 -> part-start state
  }
  __syncthreads();
  // per-lane exclusive (shift up 1; lane 0 = identity)
  float E00 = __shfl_up(A00, 1), E01 = __shfl_up(A01, 1);
  float E10 = __shfl_up(A10, 1), E11 = __shfl_up(A11, 1);
  float Ed0 = __shfl_up(d0, 1),  Ed1 = __shfl_up(d1, 1);
  if (lane == 0) { E00 = 1.f; E01 = 0.f; E10 = 0.f; E11 = 1.f; Ed0 = 0.f; Ed1 = 0.f; }
  // exclusive wave prefix P = waves 0..w-1 in order
  float P00 = 1.f, P01 = 0.f, P10 = 0.f, P11 = 1.f, Pd0 = 0.f, Pd1 = 0.f;
  for (int i = 0; i < w; ++i) {
    float W00 = wagg[i][0], W01 = wagg[i][1], W10 = wagg[i][2];
    float W11 = wagg[i][3], Wd0 = wagg[i][4], Wd1 = wagg[i][5];
    float n00 = fmaf(W00, P00, W01 * P10);
    float n01 = fmaf(W00, P01, W01 * P11);
    float n10 = fmaf(W10, P00, W11 * P10);
    float n11 = fmaf(W10, P01, W11 * P11);
    float nd0 = fmaf(W00, Pd0, fmaf(W01, Pd1, Wd0));
    float nd1 = fmaf(W10, Pd0, fmaf(W11, Pd1, Wd1));
    P00 = n00; P01 = n01; P10 = n10; P11 = n11; Pd0 = nd0; Pd1 = nd1;
  }
  // X = E after P (full in-block exclusive)
  float X00 = fmaf(E00, P00, E01 * P10);
  float X01 = fmaf(E00, P01, E01 * P11);
  float X10 = fmaf(E10, P00, E11 * P10);
  float X11 = fmaf(E10, P01, E11 * P11);
  float Xd0 = fmaf(E00, Pd0, fmaf(E01, Pd1, Ed0));
  float Xd1 = fmaf(E10, Pd0, fmaf(E11, Pd1, Ed1));
  // chunk-start state; apply
  float r0 = rowpref[0], r1 = rowpref[1];
  float s1 = fmaf(X00, r0, fmaf(X01, r1, Xd0));
  float s2 = fmaf(X10, r0, fmaf(X11, r1, Xd1));
  float4* o4 = (float4*)(out + rb + bs + t0l);
#pragma unroll
  for (int k = 0; k < 2; ++k) {
    float ys[4];
#pragma unroll
    for (int q = 0; q < 4; ++q) {
      int idx = k * 4 + q;
      float p0 = p0c[idx];
      float y = p0 + s1;
      ys[q] = y;
      float ns1 = fmaf(na1c[idx], y, fmaf(2.f, p0, s2));
      float ns2 = fmaf(na2c[idx], y, p0);
      s1 = ns1; s2 = ns2;
    }
    o4[k] = make_float4(ys[0], ys[1], ys[2], ys[3]);
  }
}

extern "C" void kernel_launch(void* const* d_in, const int* in_sizes, int n_in,
                              void* d_out, int out_size, void* d_ws, size_t ws_size,
                              hipStream_t stream) {
  const float* f0     = (const float*)d_in[0];
  const float* x      = (const float*)d_in[1];
  const float* params = (const float*)d_in[2];
  const int*   onsets = (const int*)d_in[3];
  float* out = (float*)d_out;

  char* w = (char*)d_ws;
  auto alloc = [&](size_t bytes) -> void* {
    void* p = (void*)w;
    w += (bytes + 255) & ~(size_t)255;
    return p;
  };
  unsigned short* seg_ids = (unsigned short*)alloc(sizeof(unsigned short) * B * T);
  int*    cnt      = (int*)alloc(sizeof(int) * B * WV);
  int*    onsetPos = (int*)alloc(sizeof(int) * B * MAXSEG);
  int*    nseg     = (int*)alloc(sizeof(int) * B);
  float4* segc     = (float4*)alloc(sizeof(float4) * B * MAXSEG);
  float*  segd     = (float*)alloc(sizeof(float) * B * MAXSEG);
  float*  p0g      = (float*)alloc(sizeof(float) * B * T);
  float*  aggP     = (float*)alloc(sizeof(float) * 6 * NB);
  (void)in_sizes; (void)n_in; (void)out_size; (void)ws_size;

  k_count  <<<512, 256, 0, stream>>>(onsets, cnt);
  k_segids <<<512, 256, 0, stream>>>(onsets, cnt, seg_ids, onsetPos, nseg);
  k_segavg <<<B * 64, 256, 0, stream>>>(params, onsetPos, nseg, segc, segd);
  k_compose<<<NB, 256, 0, stream>>>(f0, x, seg_ids, segc, segd, p0g, aggP);
  k_apply  <<<NB, 256, 0, stream>>>(p0g, seg_ids, segc, aggP, out);
}